// Round 9
// baseline (168.086 us; speedup 1.0000x reference)
//
#include <hip/hip_runtime.h>
#include <hip/hip_bf16.h>

#define L_SEQ    1024
#define IN_DIM   256
#define DIM_MSA  32
#define PAIR_DIM 64

typedef float f4v __attribute__((ext_vector_type(4)));

// ws layout (floats): s[1024][32] | sT[32][1024] | W2T[32][32][64] | tmpT[32][1024][64]
#define S_OFF    0
#define ST_OFF   (32 * 1024)
#define W2T_OFF  (ST_OFF + 32 * 1024)
#define TMPT_OFF (W2T_OFF + 32 * 32 * 64)

// s[i][c] = b1[c] + sum_d seq[i][d] * W1[c][d]; also sT[c][i] = s[i][c]
__global__ void k_proj1(const float* __restrict__ seq, const float* __restrict__ W1,
                        const float* __restrict__ b1, float* __restrict__ s,
                        float* __restrict__ sT) {
    int t = blockIdx.x * blockDim.x + threadIdx.x;   // 1024*32 threads
    int i = t >> 5, c = t & 31;
    const float4* sq = (const float4*)(seq + i * IN_DIM);
    const float4* w  = (const float4*)(W1  + c * IN_DIM);
    float a0 = 0.f, a1 = 0.f, a2 = 0.f, a3 = 0.f;
#pragma unroll
    for (int d4 = 0; d4 < IN_DIM / 4; ++d4) {
        float4 x = sq[d4], y = w[d4];
        a0 += x.x * y.x;  a1 += x.y * y.y;
        a2 += x.z * y.z;  a3 += x.w * y.w;
    }
    float v = b1[c] + ((a0 + a1) + (a2 + a3));
    s[t] = v;                    // s[i][c]
    sT[c * L_SEQ + i] = v;       // sT[c][i]
}

// W2T[d][c][p] = W2[p][c*32+d]   (16384 threads; thread: float4 over p)
__global__ void k_w2t(const float* __restrict__ W2, float* __restrict__ W2T) {
    int t = blockIdx.x * blockDim.x + threadIdx.x;   // 32d*32c*16q
    int q = t & 15, c = (t >> 4) & 31, d = t >> 9;
    f4v v;
    v.x = W2[(4 * q + 0) * 1024 + c * 32 + d];
    v.y = W2[(4 * q + 1) * 1024 + c * 32 + d];
    v.z = W2[(4 * q + 2) * 1024 + c * 32 + d];
    v.w = W2[(4 * q + 3) * 1024 + c * 32 + d];
    ((f4v*)W2T)[(d * 32 + c) * 16 + q] = v;
}

// tmpT[d][j][p] = sum_c s[j][c] * W2T[d][c][p]   (thread: float4 over p)
__global__ void k_proj2t(const float* __restrict__ s, const float* __restrict__ W2T,
                         float* __restrict__ tmpT) {
    int t = blockIdx.x * blockDim.x + threadIdx.x;   // 32d*1024j*16q = 524288
    int q = t & 15, j = (t >> 4) & 1023, d = t >> 14;
    const f4v*  w4 = (const f4v*)W2T + d * 32 * 16 + q;   // step 16 per c
    const float* sj = s + j * DIM_MSA;
    f4v acc = {0.f, 0.f, 0.f, 0.f};
#pragma unroll
    for (int c = 0; c < DIM_MSA; ++c)
        acc += sj[c] * w4[c * 16];
    ((f4v*)tmpT)[(d * 1024 + j) * 16 + q] = acc;          // 1KB/wave contiguous
}

// out[i][j][p] = sum_d sT[d][i]*tmpT[d][j][p] + b2[p] + pair[i][j][p]
// Wave = (i-tile 8, j-quad). lane: jj=lane>>4 (j), pq=lane&15 (float4 of p).
// Streams tmpT[d] at 1KB/instr (L2-resident); sT[d][i0..7] via SGPR s_load;
// 8 f4v accumulators are loop-carried -> cannot be sunk by regalloc.
// Epilogue pair loads + nt stores are 1KB/instr contiguous HBM traffic.
__global__ __launch_bounds__(256) void k_outer_t(
    const float* __restrict__ sT, const float* __restrict__ tmpT,
    const float* __restrict__ pair, const float* __restrict__ b2,
    float* __restrict__ out) {
    int tid  = threadIdx.x;
    int wave = tid >> 6, lane = tid & 63;
    int jj = lane >> 4, pq = lane & 15;
    int iblk = blockIdx.x & 127;                 // fast axis: i-tiles (tmpT L2 reuse)
    int jblk = blockIdx.x >> 7;
    int i0 = iblk * 8;
    int jw = jblk * 16 + wave * 4 + jj;          // this lane's j

    const f4v*  tp = (const f4v*)tmpT + jw * 16 + pq;     // d=0
    const float* sp = sT + i0;

    f4v acc0 = {0.f,0.f,0.f,0.f}, acc1 = acc0, acc2 = acc0, acc3 = acc0,
        acc4 = acc0, acc5 = acc0, acc6 = acc0, acc7 = acc0;

#pragma unroll 8
    for (int d = 0; d < 32; ++d) {
        f4v tv = tp[(size_t)d << 14];                     // tmpT[d][jw][4pq] (1KB/wave)
        f4v sA = *(const f4v*)(sp + (d << 10));           // sT[d][i0..i0+3] -> SGPR
        f4v sB = *(const f4v*)(sp + (d << 10) + 4);       // sT[d][i0+4..i0+7]
        acc0 += tv * sA.x;  acc1 += tv * sA.y;
        acc2 += tv * sA.z;  acc3 += tv * sA.w;
        acc4 += tv * sB.x;  acc5 += tv * sB.y;
        acc6 += tv * sB.z;  acc7 += tv * sB.w;
    }

    size_t base = ((size_t)i0 * L_SEQ + jw) * 16 + pq;    // f4 units; i-stride 16384
    const f4v* pp = (const f4v*)pair + base;
    f4v*       op = (f4v*)out + base;
    f4v b4 = *(const f4v*)(b2 + 4 * pq);

    f4v p0 = pp[0 * 16384], p1 = pp[1 * 16384], p2 = pp[2 * 16384], p3 = pp[3 * 16384],
        p4 = pp[4 * 16384], p5 = pp[5 * 16384], p6 = pp[6 * 16384], p7 = pp[7 * 16384];
    __builtin_nontemporal_store(acc0 + b4 + p0, op + 0 * 16384);
    __builtin_nontemporal_store(acc1 + b4 + p1, op + 1 * 16384);
    __builtin_nontemporal_store(acc2 + b4 + p2, op + 2 * 16384);
    __builtin_nontemporal_store(acc3 + b4 + p3, op + 3 * 16384);
    __builtin_nontemporal_store(acc4 + b4 + p4, op + 4 * 16384);
    __builtin_nontemporal_store(acc5 + b4 + p5, op + 5 * 16384);
    __builtin_nontemporal_store(acc6 + b4 + p6, op + 6 * 16384);
    __builtin_nontemporal_store(acc7 + b4 + p7, op + 7 * 16384);
}

extern "C" void kernel_launch(void* const* d_in, const int* in_sizes, int n_in,
                              void* d_out, int out_size, void* d_ws, size_t ws_size,
                              hipStream_t stream) {
    const float* seq  = (const float*)d_in[0];   // [1,1024,256]
    const float* pair = (const float*)d_in[1];   // [1,1024,1024,64]
    const float* W1   = (const float*)d_in[2];   // [32,256]
    const float* b1   = (const float*)d_in[3];   // [32]
    const float* W2   = (const float*)d_in[4];   // [64,1024]
    const float* b2   = (const float*)d_in[5];   // [64]
    float* out = (float*)d_out;

    float* ws     = (float*)d_ws;
    float* s_ws   = ws + S_OFF;
    float* sT_ws  = ws + ST_OFF;
    float* w2t_ws = ws + W2T_OFF;
    float* tmpT_ws = ws + TMPT_OFF;              // 8 MB

    k_proj1 <<<(L_SEQ * DIM_MSA) / 256, 256, 0, stream>>>(seq, W1, b1, s_ws, sT_ws);
    k_w2t   <<<(32 * 32 * 16) / 256, 256, 0, stream>>>(W2, w2t_ws);
    k_proj2t<<<(32 * 1024 * 16) / 256, 256, 0, stream>>>(s_ws, w2t_ws, tmpT_ws);
    k_outer_t<<<128 * 64, 256, 0, stream>>>(sT_ws, tmpT_ws, pair, b2, out);
}